// Round 4
// baseline (197.344 us; speedup 1.0000x reference)
//
#include <hip/hip_runtime.h>

#define IH 512
#define IW 512
#define OH 510
#define OW 510
#define NB 32
#define KO 16
#define RPB 30          // output rows per block (510 = 30 * 17 bands)
#define NBAND (OH / RPB)

typedef float f32x4 __attribute__((ext_vector_type(4)));
typedef float f32x2 __attribute__((ext_vector_type(2)));

// Each block: one (image n, filter o, 30-row band) -> writes 61.2 KB
// CONTIGUOUS output. 256 threads = 2 rows x 128 col-groups (4 cols each),
// looping 15 row-pairs. Per-row phase shift keeps float4 stores 16B-aligned
// (plane stride 1040400 B % 16 == 0; row stride 2040 B % 16 == 8).
__global__ __launch_bounds__(256) void conv3x3_k16_kernel(
    const float* __restrict__ x,
    const float* __restrict__ k,
    float* __restrict__ out)
{
    const int bid  = blockIdx.x;
    const int band = bid % NBAND;
    const int rest = bid / NBAND;
    const int o    = rest % KO;
    const int n    = rest / KO;

    const int t    = threadIdx.x;
    const int half = t >> 7;       // row within pair
    const int tt   = t & 127;
    const bool tail = (tt == 127);
    const int r0   = band * RPB;

    // 9 weights for this plane, thread-uniform -> SGPRs
    float w[9];
#pragma unroll
    for (int q = 0; q < 9; ++q) w[q] = k[o * 9 + q];

    const float* xn = x + (size_t)n * IH * IW;
    float* on = out + ((size_t)(n * KO + o) * OH) * OW;

#pragma unroll 1
    for (int it = 0; it < RPB / 2; ++it) {
        const int i = r0 + 2 * it + half;   // output row
        // Even i: full threads j=4tt (tail j=508); odd i: j=4tt+2 (tail j=0)
        int j;
        const bool even = (i & 1) == 0;
        if (even) j = tail ? 508 : 4 * tt;
        else      j = tail ? 0   : 4 * tt + 2;

        const float* xr = xn + (size_t)i * IW + j;

        float xv[3][6];
#pragma unroll
        for (int rr = 0; rr < 3; ++rr) {
            const float2 a = *reinterpret_cast<const float2*>(xr + rr * IW);
            const float2 b = *reinterpret_cast<const float2*>(xr + rr * IW + 2);
            xv[rr][0] = a.x; xv[rr][1] = a.y; xv[rr][2] = b.x; xv[rr][3] = b.y;
            if (!tail) {
                const float2 c = *reinterpret_cast<const float2*>(xr + rr * IW + 4);
                xv[rr][4] = c.x; xv[rr][5] = c.y;
            } else {
                xv[rr][4] = 0.0f; xv[rr][5] = 0.0f;
            }
        }

        float acc0 = 0.0f, acc1 = 0.0f, acc2 = 0.0f, acc3 = 0.0f;
#pragma unroll
        for (int rr = 0; rr < 3; ++rr) {
#pragma unroll
            for (int c = 0; c < 3; ++c) {
                const float kv = w[rr * 3 + c];
                acc0 = fmaf(xv[rr][c],     kv, acc0);
                acc1 = fmaf(xv[rr][c + 1], kv, acc1);
                acc2 = fmaf(xv[rr][c + 2], kv, acc2);
                acc3 = fmaf(xv[rr][c + 3], kv, acc3);
            }
        }

        float* p = on + (size_t)i * OW + j;
        if (!tail) {
            f32x4 v; v.x = acc0; v.y = acc1; v.z = acc2; v.w = acc3;
            __builtin_nontemporal_store(v, reinterpret_cast<f32x4*>(p));
        } else {
            f32x2 v; v.x = acc0; v.y = acc1;
            __builtin_nontemporal_store(v, reinterpret_cast<f32x2*>(p));
        }
    }
}

extern "C" void kernel_launch(void* const* d_in, const int* in_sizes, int n_in,
                              void* d_out, int out_size, void* d_ws, size_t ws_size,
                              hipStream_t stream) {
    const float* x   = (const float*)d_in[0];
    const float* ker = (const float*)d_in[1];
    float* out       = (float*)d_out;

    dim3 grid(NB * KO * NBAND);   // 8704 blocks: (n, o, band)
    dim3 block(256);
    conv3x3_k16_kernel<<<grid, block, 0, stream>>>(x, ker, out);
}